// Round 1
// baseline (459.893 us; speedup 1.0000x reference)
//
#include <hip/hip_runtime.h>
#include <math.h>

#define NN 100000
#define NE 3200000
#define OUTD 112
#define BROWS 512                 // rows per bucket (9-bit local row)
#define NBUCK 196                 // ceil(NN / BROWS)
#define FILL_CH 8192              // edges per block in hist/fill
#define FILL_B ((NE + FILL_CH - 1) / FILL_CH)   // 391
#define BLD1_T 1024               // threads for bhist/bucket_fill (16 waves)
#define SORT_T 512                // threads for csr_sort

// round-to-nearest-even fp32 -> bf16 (as raw 16 bits)
__device__ inline unsigned short f32_to_bf16(float f) {
    unsigned u = __float_as_uint(f);
    u += 0x7FFFu + ((u >> 16) & 1u);
    return (unsigned short)(u >> 16);
}
__device__ inline float bf16_bits_to_f32(unsigned b) {
    return __uint_as_float(b << 16);
}

// ---------------------------------------------------------------------------
// Kernel 1: ego = entity_embed * (1 + tanh(aux_info @ aux_W.T + aux_b))
// writes out[:,0:64] (fp32 ego, read back by layer0) + bf16 ego0h (gather).
// ---------------------------------------------------------------------------
__global__ void fuse_ego_kernel(const float* __restrict__ aux_info,
                                const float* __restrict__ entity,
                                const float* __restrict__ aux_W,
                                const float* __restrict__ aux_b,
                                unsigned short* __restrict__ ego0h,
                                float* __restrict__ out) {
    int idx = blockIdx.x * blockDim.x + threadIdx.x;
    if (idx >= NN * 64) return;
    int n = idx >> 6;
    int j = idx & 63;
    float a0 = aux_info[n * 3 + 0];
    float a1 = aux_info[n * 3 + 1];
    float a2 = aux_info[n * 3 + 2];
    float w0 = aux_W[j * 3 + 0];
    float w1 = aux_W[j * 3 + 1];
    float w2 = aux_W[j * 3 + 2];
    float t = tanhf(fmaf(a0, w0, fmaf(a1, w1, fmaf(a2, w2, aux_b[j]))));
    float e = entity[idx] * (1.0f + t);
    ego0h[idx] = f32_to_bf16(e);
    out[(size_t)n * OUTD + j] = e;
}

// ---------------------------------------------------------------------------
// CSR build, stage 1: bucket (512-row granularity) counting sort.
// ---------------------------------------------------------------------------
__global__ void bhist_kernel(const int* __restrict__ rows, int* __restrict__ gcount) {
    __shared__ int h[NBUCK];
    for (int i = threadIdx.x; i < NBUCK; i += BLD1_T) h[i] = 0;
    __syncthreads();
    int base = blockIdx.x * FILL_CH;
    int nE = NE - base; if (nE > FILL_CH) nE = FILL_CH;
    for (int i = threadIdx.x; i < nE; i += BLD1_T)
        atomicAdd(&h[rows[base + i] >> 9], 1);
    __syncthreads();
    for (int i = threadIdx.x; i < NBUCK; i += BLD1_T)
        if (h[i]) atomicAdd(&gcount[i], h[i]);
}

__global__ void bscan_kernel(const int* __restrict__ gcount,
                             int* __restrict__ bucket_base,
                             int* __restrict__ gcursor) {
    __shared__ int sh[256];
    int t = threadIdx.x;
    int v = (t < NBUCK) ? gcount[t] : 0;
    sh[t] = v;
    __syncthreads();
    for (int off = 1; off < 256; off <<= 1) {
        int u = (t >= off) ? sh[t - off] : 0;
        __syncthreads();
        sh[t] += u;
        __syncthreads();
    }
    if (t < NBUCK) {
        int excl = sh[t] - v;
        bucket_base[t] = excl;
        gcursor[t] = excl;
    }
    if (t == 255) bucket_base[NBUCK] = sh[255];
}

__global__ void bucket_fill_kernel(const int* __restrict__ rows,
                                   const int* __restrict__ cols,
                                   const float* __restrict__ vals,
                                   int* __restrict__ gcursor,
                                   int2* __restrict__ edges_b) {
    __shared__ int rowsL[FILL_CH];        // 32 KB
    __shared__ int hcnt[NBUCK];
    __shared__ int curs[NBUCK];
    int base = blockIdx.x * FILL_CH;
    int nE = NE - base; if (nE > FILL_CH) nE = FILL_CH;
    for (int i = threadIdx.x; i < NBUCK; i += BLD1_T) hcnt[i] = 0;
    __syncthreads();
    for (int i = threadIdx.x; i < nE; i += BLD1_T) {
        int r = rows[base + i];
        rowsL[i] = r;
        atomicAdd(&hcnt[r >> 9], 1);
    }
    __syncthreads();
    for (int b = threadIdx.x; b < NBUCK; b += BLD1_T) {
        int c = hcnt[b];
        curs[b] = c ? atomicAdd(&gcursor[b], c) : 0;
    }
    __syncthreads();
    for (int i = threadIdx.x; i < nE; i += BLD1_T) {
        int r = rowsL[i];
        int b = r >> 9;
        int p = atomicAdd(&curs[b], 1);
        edges_b[p] = make_int2(cols[base + i] | ((r & (BROWS - 1)) << 17),
                               __float_as_int(vals[base + i]));
    }
}

// ---------------------------------------------------------------------------
// CSR build, stage 2: within-bucket counting sort -> row-sorted PACKED edges
// (uint32 = col | bf15(val)<<17) + row_ptr.
// ---------------------------------------------------------------------------
__global__ void csr_sort_kernel(const int2* __restrict__ edges_b,
                                const int* __restrict__ bucket_base,
                                unsigned int* __restrict__ edges,
                                int* __restrict__ row_ptr) {
    __shared__ int cnt[BROWS];
    __shared__ int scn[BROWS];
    __shared__ int curs[BROWS];
    int b = blockIdx.x;
    int beg = bucket_base[b], end = bucket_base[b + 1];
    int t = threadIdx.x;
    cnt[t] = 0;
    __syncthreads();
    for (int i = beg + t; i < end; i += SORT_T)
        atomicAdd(&cnt[(edges_b[i].x >> 17) & (BROWS - 1)], 1);
    __syncthreads();
    scn[t] = cnt[t];
    __syncthreads();
    for (int off = 1; off < BROWS; off <<= 1) {
        int v = (t >= off) ? scn[t - off] : 0;
        __syncthreads();
        scn[t] += v;
        __syncthreads();
    }
    {
        int excl = scn[t] - cnt[t];
        int n = b * BROWS + t;
        if (n <= NN) row_ptr[n] = beg + excl;   // n==NN covered by last bucket
        curs[t] = beg + excl;
    }
    __syncthreads();
    for (int i = beg + t; i < end; i += SORT_T) {
        int2 e = edges_b[i];
        int rl = (e.x >> 17) & (BROWS - 1);
        int p = atomicAdd(&curs[rl], 1);
        unsigned int vb = f32_to_bf16(__int_as_float(e.y)) & 0x7FFFu;  // val>=0
        edges[p] = (unsigned int)(e.x & 0x1FFFF) | (vb << 17);
    }
}

// ---------------------------------------------------------------------------
// FUSED gather (pull segment-sum, bf16) + bi-interaction transform + l2norm.
//
// Phase 1 (gather): L = DIN/2 lanes/node, each lane owns a feature PAIR.
//   Lane mapping n=tid/L, j=tid%L == transform mapping (L == DOUT for both
//   layers), so the same lanes that gathered (a0,a1) stage the HOISTED
//   s=ego+side, p=ego*side pairs straight into LDS — (eg+sd)/(eg*sd) is
//   computed once per node instead of DOUT times, and `side` never touches
//   global memory (saves 51 MB round-trip per layer-0).
// Phase 2 (transform): thread (m, jt): s/p read back as BROADCAST float4
//   (ds_read_b128, all jt lanes same address), W as conflict-free scalar
//   ([k][jt], stride DOUT+1 -> bank (k+jt)%32). Transform LDS/VALU work
//   overlaps with other blocks' gather L2-miss stalls (gather: 48% VALUBusy,
//   0 LDS — the pipes the transform needs are idle there).
// Numerics identical to the unfused version (same accumulation order).
// ---------------------------------------------------------------------------
template <int DIN, int DOUT>
__global__ __launch_bounds__(256) void fused_gather_layer_kernel(
    const ushort2* __restrict__ egoh,
    const unsigned int* __restrict__ edges,
    const int* __restrict__ row_ptr,
    const float* __restrict__ ego, int ego_stride,
    const float* __restrict__ W1, const float* __restrict__ b1,
    const float* __restrict__ W2, const float* __restrict__ b2,
    float* __restrict__ ego_next,            // nullable
    unsigned short* __restrict__ ego_next_h, // nullable
    float* __restrict__ out, int out_off)
{
    constexpr int L  = DIN / 2;     // lanes per node in gather
    constexpr int NB = 256 / L;     // nodes per block (NN % NB == 0)
    static_assert(L == DOUT, "gather/transform lane mapping must coincide");

    __shared__ float W1t[DIN][DOUT + 1];   // [k][j], conflict-free scalar reads
    __shared__ float W2t[DIN][DOUT + 1];
    __shared__ float sArr[NB][DIN + 4];    // +4 pad: 16B-aligned rows, banks spread
    __shared__ float pArr[NB][DIN + 4];

    for (int i = threadIdx.x; i < DIN * DOUT; i += 256) {
        int jj = i / DIN;
        int kk = i - jj * DIN;
        W1t[kk][jj] = W1[i];
        W2t[kk][jj] = W2[i];
    }

    const int m = threadIdx.x / L;
    const int j = threadIdx.x % L;
    const int n = blockIdx.x * NB + m;     // grid sized exactly: always < NN

    // ---- phase 1: gather + hoisted s/p staging ----
    {
        int beg = row_ptr[n];
        int end = row_ptr[n + 1];
        float a0 = 0.0f, a1 = 0.0f;
        int i = beg;
        for (; i + 8 <= end; i += 8) {
            unsigned int e[8];
            ushort2 gv[8];
#pragma unroll
            for (int k = 0; k < 8; ++k) e[k] = edges[i + k];
#pragma unroll
            for (int k = 0; k < 8; ++k) gv[k] = egoh[(size_t)(e[k] & 0x1FFFFu) * L + j];
#pragma unroll
            for (int k = 0; k < 8; ++k) {
                float v = bf16_bits_to_f32(e[k] >> 17);   // sign=0
                a0 = fmaf(v, bf16_bits_to_f32(gv[k].x), a0);
                a1 = fmaf(v, bf16_bits_to_f32(gv[k].y), a1);
            }
        }
        for (; i < end; ++i) {
            unsigned int e = edges[i];
            ushort2 g = egoh[(size_t)(e & 0x1FFFFu) * L + j];
            float v = bf16_bits_to_f32(e >> 17);
            a0 = fmaf(v, bf16_bits_to_f32(g.x), a0);
            a1 = fmaf(v, bf16_bits_to_f32(g.y), a1);
        }
        float e0 = ego[(size_t)n * ego_stride + 2 * j];
        float e1 = ego[(size_t)n * ego_stride + 2 * j + 1];
        *(float2*)&sArr[m][2 * j] = make_float2(e0 + a0, e1 + a1);
        *(float2*)&pArr[m][2 * j] = make_float2(e0 * a0, e1 * a1);
    }
    __syncthreads();

    // ---- phase 2: bi-interaction transform + l2norm ----
    const int mt = threadIdx.x / DOUT;
    const int jt = threadIdx.x % DOUT;
    const int nt = blockIdx.x * NB + mt;

    float s  = b1[jt];
    float bb = b2[jt];
#pragma unroll
    for (int k = 0; k < DIN; k += 4) {
        float4 sv = *(const float4*)&sArr[mt][k];   // broadcast across jt lanes
        float4 pv = *(const float4*)&pArr[mt][k];
        s  = fmaf(sv.x, W1t[k + 0][jt], s);
        s  = fmaf(sv.y, W1t[k + 1][jt], s);
        s  = fmaf(sv.z, W1t[k + 2][jt], s);
        s  = fmaf(sv.w, W1t[k + 3][jt], s);
        bb = fmaf(pv.x, W2t[k + 0][jt], bb);
        bb = fmaf(pv.y, W2t[k + 1][jt], bb);
        bb = fmaf(pv.z, W2t[k + 2][jt], bb);
        bb = fmaf(pv.w, W2t[k + 3][jt], bb);
    }
    s  = (s  > 0.0f) ? s  : 0.01f * s;
    bb = (bb > 0.0f) ? bb : 0.01f * bb;
    float v = s + bb;
    if (ego_next)   ego_next[(size_t)nt * DOUT + jt] = v;
    if (ego_next_h) ego_next_h[(size_t)nt * DOUT + jt] = f32_to_bf16(v);

    float sq = v * v;
#pragma unroll
    for (int off = DOUT / 2; off > 0; off >>= 1)
        sq += __shfl_xor(sq, off, DOUT);
    float norm = sqrtf(sq);
    norm = (norm > 1e-12f) ? norm : 1e-12f;
    out[(size_t)nt * OUTD + out_off + jt] = v / norm;
}

// ---------------------------------------------------------------------------
extern "C" void kernel_launch(void* const* d_in, const int* in_sizes, int n_in,
                              void* d_out, int out_size, void* d_ws, size_t ws_size,
                              hipStream_t stream) {
    const float* aux_info  = (const float*)d_in[0];
    const float* entity    = (const float*)d_in[1];
    const float* aux_W     = (const float*)d_in[2];
    const float* aux_b     = (const float*)d_in[3];
    const float* edge_vals = (const float*)d_in[4];
    const int*   edge_rows = (const int*)d_in[5];
    const int*   edge_cols = (const int*)d_in[6];
    const float* W1_0 = (const float*)d_in[7];
    const float* b1_0 = (const float*)d_in[8];
    const float* W2_0 = (const float*)d_in[9];
    const float* b2_0 = (const float*)d_in[10];
    const float* W1_1 = (const float*)d_in[11];
    const float* b1_1 = (const float*)d_in[12];
    const float* W2_1 = (const float*)d_in[13];
    const float* b2_1 = (const float*)d_in[14];
    float* out = (float*)d_out;

    // workspace layout (4-byte words).
    //   edges_b (stage-1) is dead after csr_sort; nothing aliases the live
    //   buffers across a fused kernel (ego1h must NOT alias ego0h: the fused
    //   layer-0 kernel writes ego1h while other blocks still gather ego0h).
    float* region0 = (float*)d_ws;
    int2*  edges_b = (int2*)region0;                                     // 2*NE words
    unsigned short* ego0h = (unsigned short*)(region0 + (size_t)NE * 2); // NN*32 words
    unsigned int* edges = (unsigned int*)((float*)ego0h + (size_t)NN * 32); // NE words
    float* ego1 = (float*)(edges + NE);                                  // NN*32 words
    unsigned short* ego1h = (unsigned short*)(ego1 + (size_t)NN * 32);   // NN*16 words
    int* row_ptr     = (int*)((float*)ego1h + (size_t)NN * 16);
    int* bucket_base = row_ptr + NN + 1;
    int* gcount      = bucket_base + NBUCK + 1;            // reused as cursor

    // --- CSR build (graph shared by both layers) ---
    hipMemsetAsync(gcount, 0, (size_t)NBUCK * sizeof(int), stream);
    bhist_kernel<<<FILL_B, BLD1_T, 0, stream>>>(edge_rows, gcount);
    bscan_kernel<<<1, 256, 0, stream>>>(gcount, bucket_base, gcount);
    bucket_fill_kernel<<<FILL_B, BLD1_T, 0, stream>>>(
        edge_rows, edge_cols, edge_vals, gcount, edges_b);
    csr_sort_kernel<<<NBUCK, SORT_T, 0, stream>>>(edges_b, bucket_base, edges, row_ptr);

    // --- 1) holographic fusion -> out[:,0:64] (fp32 ego) + bf16 ego0h ---
    {
        int total = NN * 64;
        fuse_ego_kernel<<<(total + 255) / 256, 256, 0, stream>>>(
            aux_info, entity, aux_W, aux_b, ego0h, out);
    }
    // --- 2) layer 0: fused gather + transform -> ego1 (+bf16), out[:,64:96] ---
    fused_gather_layer_kernel<64, 32><<<NN / 8, 256, 0, stream>>>(
        (const ushort2*)ego0h, edges, row_ptr, out, OUTD,
        W1_0, b1_0, W2_0, b2_0, ego1, ego1h, out, 64);
    // --- 3) layer 1: fused gather + transform -> out[:,96:112] ---
    fused_gather_layer_kernel<32, 16><<<NN / 16, 256, 0, stream>>>(
        (const ushort2*)ego1h, edges, row_ptr, ego1, 32,
        W1_1, b1_1, W2_1, b2_1, nullptr, nullptr, out, 96);
}

// Round 2
// 455.709 us; speedup vs baseline: 1.0092x; 1.0092x over previous
//
#include <hip/hip_runtime.h>
#include <math.h>

#define NN 100000
#define NE 3200000
#define OUTD 112
#define BROWS 512                 // rows per bucket (9-bit local row)
#define NBUCK 196                 // ceil(NN / BROWS)
#define FILL_CH 8192              // edges per block in hist/fill
#define FILL_B ((NE + FILL_CH - 1) / FILL_CH)   // 391
#define BLD1_T 1024               // threads for bhist/bucket_fill (16 waves)
#define SORT_T 512                // threads for csr_sort

// round-to-nearest-even fp32 -> bf16 (as raw 16 bits)
__device__ inline unsigned short f32_to_bf16(float f) {
    unsigned u = __float_as_uint(f);
    u += 0x7FFFu + ((u >> 16) & 1u);
    return (unsigned short)(u >> 16);
}
__device__ inline float bf16_bits_to_f32(unsigned b) {
    return __uint_as_float(b << 16);
}

// ---------------------------------------------------------------------------
// Kernel 1: ego = entity_embed * (1 + tanh(aux_info @ aux_W.T + aux_b))
// writes out[:,0:64] (fp32 ego, read back by layer0) + bf16 ego0h (gather).
// ---------------------------------------------------------------------------
__global__ void fuse_ego_kernel(const float* __restrict__ aux_info,
                                const float* __restrict__ entity,
                                const float* __restrict__ aux_W,
                                const float* __restrict__ aux_b,
                                unsigned short* __restrict__ ego0h,
                                float* __restrict__ out) {
    int idx = blockIdx.x * blockDim.x + threadIdx.x;
    if (idx >= NN * 64) return;
    int n = idx >> 6;
    int j = idx & 63;
    float a0 = aux_info[n * 3 + 0];
    float a1 = aux_info[n * 3 + 1];
    float a2 = aux_info[n * 3 + 2];
    float w0 = aux_W[j * 3 + 0];
    float w1 = aux_W[j * 3 + 1];
    float w2 = aux_W[j * 3 + 2];
    float t = tanhf(fmaf(a0, w0, fmaf(a1, w1, fmaf(a2, w2, aux_b[j]))));
    float e = entity[idx] * (1.0f + t);
    ego0h[idx] = f32_to_bf16(e);
    out[(size_t)n * OUTD + j] = e;
}

// ---------------------------------------------------------------------------
// CSR build, stage 1: bucket (512-row granularity) counting sort.
// ---------------------------------------------------------------------------
__global__ void bhist_kernel(const int* __restrict__ rows, int* __restrict__ gcount) {
    __shared__ int h[NBUCK];
    for (int i = threadIdx.x; i < NBUCK; i += BLD1_T) h[i] = 0;
    __syncthreads();
    int base = blockIdx.x * FILL_CH;
    int nE = NE - base; if (nE > FILL_CH) nE = FILL_CH;
    for (int i = threadIdx.x; i < nE; i += BLD1_T)
        atomicAdd(&h[rows[base + i] >> 9], 1);
    __syncthreads();
    for (int i = threadIdx.x; i < NBUCK; i += BLD1_T)
        if (h[i]) atomicAdd(&gcount[i], h[i]);
}

__global__ void bscan_kernel(const int* __restrict__ gcount,
                             int* __restrict__ bucket_base,
                             int* __restrict__ gcursor) {
    __shared__ int sh[256];
    int t = threadIdx.x;
    int v = (t < NBUCK) ? gcount[t] : 0;
    sh[t] = v;
    __syncthreads();
    for (int off = 1; off < 256; off <<= 1) {
        int u = (t >= off) ? sh[t - off] : 0;
        __syncthreads();
        sh[t] += u;
        __syncthreads();
    }
    if (t < NBUCK) {
        int excl = sh[t] - v;
        bucket_base[t] = excl;
        gcursor[t] = excl;
    }
    if (t == 255) bucket_base[NBUCK] = sh[255];
}

__global__ void bucket_fill_kernel(const int* __restrict__ rows,
                                   const int* __restrict__ cols,
                                   const float* __restrict__ vals,
                                   int* __restrict__ gcursor,
                                   int2* __restrict__ edges_b) {
    __shared__ int rowsL[FILL_CH];        // 32 KB
    __shared__ int hcnt[NBUCK];
    __shared__ int curs[NBUCK];
    int base = blockIdx.x * FILL_CH;
    int nE = NE - base; if (nE > FILL_CH) nE = FILL_CH;
    for (int i = threadIdx.x; i < NBUCK; i += BLD1_T) hcnt[i] = 0;
    __syncthreads();
    for (int i = threadIdx.x; i < nE; i += BLD1_T) {
        int r = rows[base + i];
        rowsL[i] = r;
        atomicAdd(&hcnt[r >> 9], 1);
    }
    __syncthreads();
    for (int b = threadIdx.x; b < NBUCK; b += BLD1_T) {
        int c = hcnt[b];
        curs[b] = c ? atomicAdd(&gcursor[b], c) : 0;
    }
    __syncthreads();
    for (int i = threadIdx.x; i < nE; i += BLD1_T) {
        int r = rowsL[i];
        int b = r >> 9;
        int p = atomicAdd(&curs[b], 1);
        edges_b[p] = make_int2(cols[base + i] | ((r & (BROWS - 1)) << 17),
                               __float_as_int(vals[base + i]));
    }
}

// ---------------------------------------------------------------------------
// CSR build, stage 2: within-bucket counting sort -> row-sorted PACKED edges
// (uint32 = col | bf15(val)<<17) + row_ptr.
// ---------------------------------------------------------------------------
__global__ void csr_sort_kernel(const int2* __restrict__ edges_b,
                                const int* __restrict__ bucket_base,
                                unsigned int* __restrict__ edges,
                                int* __restrict__ row_ptr) {
    __shared__ int cnt[BROWS];
    __shared__ int scn[BROWS];
    __shared__ int curs[BROWS];
    int b = blockIdx.x;
    int beg = bucket_base[b], end = bucket_base[b + 1];
    int t = threadIdx.x;
    cnt[t] = 0;
    __syncthreads();
    for (int i = beg + t; i < end; i += SORT_T)
        atomicAdd(&cnt[(edges_b[i].x >> 17) & (BROWS - 1)], 1);
    __syncthreads();
    scn[t] = cnt[t];
    __syncthreads();
    for (int off = 1; off < BROWS; off <<= 1) {
        int v = (t >= off) ? scn[t - off] : 0;
        __syncthreads();
        scn[t] += v;
        __syncthreads();
    }
    {
        int excl = scn[t] - cnt[t];
        int n = b * BROWS + t;
        if (n <= NN) row_ptr[n] = beg + excl;   // n==NN covered by last bucket
        curs[t] = beg + excl;
    }
    __syncthreads();
    for (int i = beg + t; i < end; i += SORT_T) {
        int2 e = edges_b[i];
        int rl = (e.x >> 17) & (BROWS - 1);
        int p = atomicAdd(&curs[rl], 1);
        unsigned int vb = f32_to_bf16(__int_as_float(e.y)) & 0x7FFFu;  // val>=0
        edges[p] = (unsigned int)(e.x & 0x1FFFF) | (vb << 17);
    }
}

// ---------------------------------------------------------------------------
// FUSED gather (pull segment-sum, bf16) + bi-interaction transform + l2norm.
//
// WAVE-SYNCHRONOUS: no block barrier between gather and transform.
//   L == DOUT, so gather mapping (m=tid/L, j=tid%L) == transform mapping, and
//   each L-lane node group (L=32 layer0, L=16 layer1) lies entirely inside one
//   64-lane wave. All s/p communication is intra-wave through LDS: DS-pipe ops
//   from one wave complete in order, the compiler inserts the lgkmcnt for the
//   read, and __builtin_amdgcn_wave_barrier() (zero-cost) pins the ordering.
//   The ONLY __syncthreads is after the W-tile load, BEFORE the variable-
//   length gather — so degree variance (Poisson(32)) no longer couples 8
//   nodes at a block barrier (R1's 1.44x gather inflation + zero overlap:
//   153.7us vs 122us unfused). Waves retire independently; transform VALU/LDS
//   work hides under other waves' gather L2-miss stalls.
// Numerics identical to the unfused version (same accumulation order).
// ---------------------------------------------------------------------------
template <int DIN, int DOUT>
__global__ __launch_bounds__(256) void fused_gather_layer_kernel(
    const ushort2* __restrict__ egoh,
    const unsigned int* __restrict__ edges,
    const int* __restrict__ row_ptr,
    const float* __restrict__ ego, int ego_stride,
    const float* __restrict__ W1, const float* __restrict__ b1,
    const float* __restrict__ W2, const float* __restrict__ b2,
    float* __restrict__ ego_next,            // nullable
    unsigned short* __restrict__ ego_next_h, // nullable
    float* __restrict__ out, int out_off)
{
    constexpr int L  = DIN / 2;     // lanes per node in gather
    constexpr int NB = 256 / L;     // nodes per block (NN % NB == 0)
    static_assert(L == DOUT, "gather/transform lane mapping must coincide");
    static_assert(L <= 32, "node group must fit inside one wave");

    __shared__ float W1t[DIN][DOUT + 1];   // +1: conflict-free load AND read
    __shared__ float W2t[DIN][DOUT + 1];
    __shared__ float sArr[NB][DIN + 4];    // +4 pad: rows 16B-aligned
    __shared__ float pArr[NB][DIN + 4];

    for (int i = threadIdx.x; i < DIN * DOUT; i += 256) {
        int jj = i / DIN;
        int kk = i - jj * DIN;
        W1t[kk][jj] = W1[i];
        W2t[kk][jj] = W2[i];
    }
    __syncthreads();   // W ready. Only block-wide barrier: before gather.

    const int m = threadIdx.x / L;
    const int j = threadIdx.x % L;
    const int n = blockIdx.x * NB + m;     // grid sized exactly: always < NN

    // ---- phase 1: gather + hoisted s/p staging (intra-wave) ----
    {
        int beg = row_ptr[n];
        int end = row_ptr[n + 1];
        float a0 = 0.0f, a1 = 0.0f;
        int i = beg;
        for (; i + 8 <= end; i += 8) {
            unsigned int e[8];
            ushort2 gv[8];
#pragma unroll
            for (int k = 0; k < 8; ++k) e[k] = edges[i + k];
#pragma unroll
            for (int k = 0; k < 8; ++k) gv[k] = egoh[(size_t)(e[k] & 0x1FFFFu) * L + j];
#pragma unroll
            for (int k = 0; k < 8; ++k) {
                float v = bf16_bits_to_f32(e[k] >> 17);   // sign=0
                a0 = fmaf(v, bf16_bits_to_f32(gv[k].x), a0);
                a1 = fmaf(v, bf16_bits_to_f32(gv[k].y), a1);
            }
        }
        for (; i < end; ++i) {
            unsigned int e = edges[i];
            ushort2 g = egoh[(size_t)(e & 0x1FFFFu) * L + j];
            float v = bf16_bits_to_f32(e >> 17);
            a0 = fmaf(v, bf16_bits_to_f32(g.x), a0);
            a1 = fmaf(v, bf16_bits_to_f32(g.y), a1);
        }
        float e0 = ego[(size_t)n * ego_stride + 2 * j];
        float e1 = ego[(size_t)n * ego_stride + 2 * j + 1];
        *(float2*)&sArr[m][2 * j] = make_float2(e0 + a0, e1 + a1);
        *(float2*)&pArr[m][2 * j] = make_float2(e0 * a0, e1 * a1);
    }
    // Intra-wave LDS RAW: DS pipe is in-order per wave; pin compiler ordering.
    __builtin_amdgcn_wave_barrier();

    // ---- phase 2: bi-interaction transform + l2norm (same m/j mapping) ----
    float s  = b1[j];
    float bb = b2[j];
#pragma unroll
    for (int k = 0; k < DIN; k += 4) {
        float4 sv = *(const float4*)&sArr[m][k];   // broadcast across j lanes
        float4 pv = *(const float4*)&pArr[m][k];
        s  = fmaf(sv.x, W1t[k + 0][j], s);
        s  = fmaf(sv.y, W1t[k + 1][j], s);
        s  = fmaf(sv.z, W1t[k + 2][j], s);
        s  = fmaf(sv.w, W1t[k + 3][j], s);
        bb = fmaf(pv.x, W2t[k + 0][j], bb);
        bb = fmaf(pv.y, W2t[k + 1][j], bb);
        bb = fmaf(pv.z, W2t[k + 2][j], bb);
        bb = fmaf(pv.w, W2t[k + 3][j], bb);
    }
    s  = (s  > 0.0f) ? s  : 0.01f * s;
    bb = (bb > 0.0f) ? bb : 0.01f * bb;
    float v = s + bb;
    if (ego_next)   ego_next[(size_t)n * DOUT + j] = v;
    if (ego_next_h) ego_next_h[(size_t)n * DOUT + j] = f32_to_bf16(v);

    float sq = v * v;
#pragma unroll
    for (int off = DOUT / 2; off > 0; off >>= 1)
        sq += __shfl_xor(sq, off, DOUT);
    float norm = sqrtf(sq);
    norm = (norm > 1e-12f) ? norm : 1e-12f;
    out[(size_t)n * OUTD + out_off + j] = v / norm;
}

// ---------------------------------------------------------------------------
extern "C" void kernel_launch(void* const* d_in, const int* in_sizes, int n_in,
                              void* d_out, int out_size, void* d_ws, size_t ws_size,
                              hipStream_t stream) {
    const float* aux_info  = (const float*)d_in[0];
    const float* entity    = (const float*)d_in[1];
    const float* aux_W     = (const float*)d_in[2];
    const float* aux_b     = (const float*)d_in[3];
    const float* edge_vals = (const float*)d_in[4];
    const int*   edge_rows = (const int*)d_in[5];
    const int*   edge_cols = (const int*)d_in[6];
    const float* W1_0 = (const float*)d_in[7];
    const float* b1_0 = (const float*)d_in[8];
    const float* W2_0 = (const float*)d_in[9];
    const float* b2_0 = (const float*)d_in[10];
    const float* W1_1 = (const float*)d_in[11];
    const float* b1_1 = (const float*)d_in[12];
    const float* W2_1 = (const float*)d_in[13];
    const float* b2_1 = (const float*)d_in[14];
    float* out = (float*)d_out;

    // workspace layout (4-byte words).
    //   edges_b (stage-1) is dead after csr_sort; nothing aliases the live
    //   buffers across a fused kernel (ego1h must NOT alias ego0h: the fused
    //   layer-0 kernel writes ego1h while other blocks still gather ego0h).
    float* region0 = (float*)d_ws;
    int2*  edges_b = (int2*)region0;                                     // 2*NE words
    unsigned short* ego0h = (unsigned short*)(region0 + (size_t)NE * 2); // NN*32 words
    unsigned int* edges = (unsigned int*)((float*)ego0h + (size_t)NN * 32); // NE words
    float* ego1 = (float*)(edges + NE);                                  // NN*32 words
    unsigned short* ego1h = (unsigned short*)(ego1 + (size_t)NN * 32);   // NN*16 words
    int* row_ptr     = (int*)((float*)ego1h + (size_t)NN * 16);
    int* bucket_base = row_ptr + NN + 1;
    int* gcount      = bucket_base + NBUCK + 1;            // reused as cursor

    // --- CSR build (graph shared by both layers) ---
    hipMemsetAsync(gcount, 0, (size_t)NBUCK * sizeof(int), stream);
    bhist_kernel<<<FILL_B, BLD1_T, 0, stream>>>(edge_rows, gcount);
    bscan_kernel<<<1, 256, 0, stream>>>(gcount, bucket_base, gcount);
    bucket_fill_kernel<<<FILL_B, BLD1_T, 0, stream>>>(
        edge_rows, edge_cols, edge_vals, gcount, edges_b);
    csr_sort_kernel<<<NBUCK, SORT_T, 0, stream>>>(edges_b, bucket_base, edges, row_ptr);

    // --- 1) holographic fusion -> out[:,0:64] (fp32 ego) + bf16 ego0h ---
    {
        int total = NN * 64;
        fuse_ego_kernel<<<(total + 255) / 256, 256, 0, stream>>>(
            aux_info, entity, aux_W, aux_b, ego0h, out);
    }
    // --- 2) layer 0: fused gather + transform -> ego1 (+bf16), out[:,64:96] ---
    fused_gather_layer_kernel<64, 32><<<NN / 8, 256, 0, stream>>>(
        (const ushort2*)ego0h, edges, row_ptr, out, OUTD,
        W1_0, b1_0, W2_0, b2_0, ego1, ego1h, out, 64);
    // --- 3) layer 1: fused gather + transform -> out[:,96:112] ---
    fused_gather_layer_kernel<32, 16><<<NN / 16, 256, 0, stream>>>(
        (const ushort2*)ego1h, edges, row_ptr, ego1, 32,
        W1_1, b1_1, W2_1, b2_1, nullptr, nullptr, out, 96);
}